// Round 5
// baseline (235.256 us; speedup 1.0000x reference)
//
#include <hip/hip_runtime.h>
#include <cstdint>
#include <cstddef>

// B=32 batch, K=4096 complex input pixels, N=4096 complex outputs.
// out[b,n] = sum_k (e_in[b,k]*ts[k]) * w[k,n]   (complex)
// W flat layout: w[k*4096 + n].
// OUTPUT (deduced R0-R4): float32, 262144 elems, PLANAR:
//   out[0      .. 131071] = real plane  (b*4096 + n)
//   out[131072 .. 262143] = imag plane
#define KC 4096
#define NN 4096
#define NB 32
#define KCH 64   // k-chunk staged in LDS per block iteration
#define HALF (NB * NN)   // 131072

// ---------------------------------------------------------------------------
// Kernel 1: modulated[b,k] = e_in[b,k] * (sigmoid(amp[k]) * exp(i*phase[k]))
// fp32, stored k-major: wsM[k*32 + b] = (re, im)
// ---------------------------------------------------------------------------
__global__ __launch_bounds__(256) void prep_kernel(
    const float* __restrict__ in_re, const float* __restrict__ in_im,
    const float* __restrict__ amp,   const float* __restrict__ phase,
    float2* __restrict__ wsM)
{
    int tid = blockIdx.x * 256 + threadIdx.x;   // 32*4096 threads
    int b = tid >> 12;
    int k = tid & (KC - 1);
    float er = in_re[tid], ei = in_im[tid];
    float a = amp[k], p = phase[k];
    float s = 1.0f / (1.0f + expf(-a));
    float sn, cs;
    sincosf(p, &sn, &cs);
    float tr = s * cs, ti = s * sn;
    float2 m;
    m.x = er * tr - ei * ti;
    m.y = er * ti + ei * tr;
    wsM[(size_t)k * NB + b] = m;
}

// ---------------------------------------------------------------------------
// Kernel 2: split-K fp32 complex GEMM, plain VALU (audited; unchanged from R4).
// Block: 256 threads = 4 waves. lane -> n (64 consecutive columns, coalesced
// W loads); wave w -> batches 8w..8w+7 (8 complex accumulators per thread).
// m-tile (KCH x 32 complex = 16 KB) staged in LDS; inner reads are
// same-address broadcasts via float4 (2 complex per ds_read_b128).
// Partials wsP[s][b][n] as float2.
// ---------------------------------------------------------------------------
__global__ __launch_bounds__(256) void gemm_kernel(
    const float* __restrict__ w_re, const float* __restrict__ w_im,
    const float2* __restrict__ wsM, float2* __restrict__ wsP, int ksplit)
{
    __shared__ float4 mch[KCH * NB / 2];   // 16 KB; [kk*16 + pair] = 2 complex
    const int t    = threadIdx.x;
    const int lane = t & 63;
    const int wave = t >> 6;                 // batch group: b = 8*wave + j
    const int n    = blockIdx.x * 64 + lane;
    const int s    = blockIdx.y;
    const int k0   = s * ksplit;

    float accR[8], accI[8];
#pragma unroll
    for (int j = 0; j < 8; ++j) { accR[j] = 0.f; accI[j] = 0.f; }

    for (int kc = 0; kc < ksplit; kc += KCH) {
        __syncthreads();   // protect previous chunk's readers
        const float4* src = (const float4*)(wsM + (size_t)(k0 + kc) * NB);
#pragma unroll
        for (int i = 0; i < 4; ++i) {
            int idx = t + 256 * i;           // 0..1023 float4s, coalesced
            mch[idx] = src[idx];
        }
        __syncthreads();

        const float* pr = w_re + (size_t)(k0 + kc) * NN + n;
        const float* pi = w_im + (size_t)(k0 + kc) * NN + n;
#pragma unroll 4
        for (int kk = 0; kk < KCH; ++kk) {
            float wr = pr[(size_t)kk * NN];
            float wi = pi[(size_t)kk * NN];
#pragma unroll
            for (int jp = 0; jp < 4; ++jp) {       // pair = 2 complex m-values
                float4 m2 = mch[kk * 16 + wave * 4 + jp];   // broadcast
                int j = 2 * jp;
                accR[j]     = fmaf(m2.x, wr, fmaf(-m2.y, wi, accR[j]));
                accI[j]     = fmaf(m2.x, wi, fmaf( m2.y, wr, accI[j]));
                accR[j + 1] = fmaf(m2.z, wr, fmaf(-m2.w, wi, accR[j + 1]));
                accI[j + 1] = fmaf(m2.z, wi, fmaf( m2.w, wr, accI[j + 1]));
            }
        }
    }

#pragma unroll
    for (int j = 0; j < 8; ++j) {
        int b = wave * 8 + j;
        float2 v; v.x = accR[j]; v.y = accI[j];
        wsP[((size_t)s * NB + b) * NN + n] = v;
    }
}

// ---------------------------------------------------------------------------
// Kernel 3: out planar: out[b*4096+n] = sum_s re;  out[131072 + ..] = sum_s im
// ---------------------------------------------------------------------------
__global__ __launch_bounds__(256) void reduce_kernel(
    const float2* __restrict__ wsP, float* __restrict__ out, int S)
{
    int tid = blockIdx.x * 256 + threadIdx.x;   // NB*NN = 131072 complex
    float re = 0.f, im = 0.f;
    for (int s = 0; s < S; ++s) {
        float2 v = wsP[(size_t)s * (NB * NN) + tid];
        re += v.x; im += v.y;
    }
    out[tid]        = re;
    out[HALF + tid] = im;
}

extern "C" void kernel_launch(void* const* d_in, const int* in_sizes, int n_in,
                              void* d_out, int out_size, void* d_ws, size_t ws_size,
                              hipStream_t stream)
{
    const float* in_re  = (const float*)d_in[0];
    const float* in_im  = (const float*)d_in[1];
    const float* w_re   = (const float*)d_in[2];
    const float* w_im   = (const float*)d_in[3];
    const float* amp    = (const float*)d_in[4];
    const float* phase  = (const float*)d_in[5];

    const size_t M_BYTES = (size_t)KC * NB * sizeof(float2);   // 1 MB
    float2* wsM = (float2*)d_ws;
    float2* wsP = (float2*)((char*)d_ws + M_BYTES);

    // largest split-K whose fp32 partial buffer fits the workspace
    int S = 16;
    while (S > 1 && M_BYTES + (size_t)S * NB * NN * sizeof(float2) > ws_size) S >>= 1;
    int ksplit = KC / S;

    prep_kernel<<<dim3((NB * KC) / 256), dim3(256), 0, stream>>>(
        in_re, in_im, amp, phase, wsM);

    gemm_kernel<<<dim3(NN / 64, S), dim3(256), 0, stream>>>(
        w_re, w_im, wsM, wsP, ksplit);

    reduce_kernel<<<dim3((NB * NN) / 256), dim3(256), 0, stream>>>(
        wsP, (float*)d_out, S);
}

// Round 6
// 166.948 us; speedup vs baseline: 1.4092x; 1.4092x over previous
//
#include <hip/hip_runtime.h>
#include <cstdint>
#include <cstddef>

// B=32 batch, K=4096 complex input pixels, N=4096 complex outputs.
// out[b,n] = sum_k (e_in[b,k]*ts[k]) * w[k,n]   (complex)
// Real-GEMM formulation, K'=8192 interleaved (re,im):
//   A[b][2k]=m_re, A[b][2k+1]=m_im
//   B_re[2k][n]=w_re, B_re[2k+1][n]=-w_im  -> out_re
//   B_im[2k][n]=w_im, B_im[2k+1][n]= w_re  -> out_im
// OUTPUT (established R5): float32 PLANAR — [re-plane 131072][im-plane 131072].
#define KC 4096
#define NN 4096
#define NB 32
#define HALF (NB * NN)

typedef __attribute__((ext_vector_type(8))) short  bf16x8;  // 8 bf16 (4 VGPRs)
typedef __attribute__((ext_vector_type(16))) float f32x16;  // 32x32 MFMA acc

__device__ __forceinline__ unsigned short f2bf(float f) {
    union { float f; unsigned u; } v; v.f = f;
    unsigned r = v.u + 0x7fffu + ((v.u >> 16) & 1u);
    return (unsigned short)(r >> 16);
}

// ---------------------------------------------------------------------------
// Kernel 1: modulated[b,k] = e_in[b,k] * (sigmoid(amp[k]) * exp(i*phase[k]))
// bf16 pairs in MFMA-A octet order: k'=2k+(re:0/im:1), octet o=k'>>3 (=k>>2),
// slot r=k'&7; dword index = ((k>>2)*32 + b)*4 + (k&3), re lo16 / im hi16.
// (Numerics verified correct by R1==R4 absmax identity.)
// ---------------------------------------------------------------------------
__global__ __launch_bounds__(256) void prep_kernel(
    const float* __restrict__ in_re, const float* __restrict__ in_im,
    const float* __restrict__ amp,   const float* __restrict__ phase,
    uint32_t* __restrict__ wsA)
{
    int tid = blockIdx.x * 256 + threadIdx.x;   // 32*4096 threads
    int b = tid >> 12;
    int k = tid & (KC - 1);
    float er = in_re[tid], ei = in_im[tid];
    float a = amp[k], p = phase[k];
    float s = 1.0f / (1.0f + expf(-a));
    float sn, cs;
    sincosf(p, &sn, &cs);
    float tr = s * cs, ti = s * sn;
    float mr = er * tr - ei * ti;
    float mi = er * ti + ei * tr;
    uint32_t pk = (uint32_t)f2bf(mr) | ((uint32_t)f2bf(mi) << 16);
    wsA[((((k >> 2) << 5) + b) << 2) | (k & 3)] = pk;
}

// ---------------------------------------------------------------------------
// Kernel 2: split-K complex GEMM via 2x mfma_f32_32x32x16_bf16 per step.
// Wave: 32 n-cols x all 32 batches. Lane: h=lane>>5 (K'-octet half),
// l32=lane&31 (m for A / n for B). Per step (8 complex k): 1 A-frag
// (global dwordx4 from wsA) + 8 coalesced W dwords -> pack B_re/B_im -> 2 MFMA.
// No LDS. Partials wsP[s][b][n] float2.
// ---------------------------------------------------------------------------
__global__ __launch_bounds__(256) void gemm_kernel(
    const float* __restrict__ w_re, const float* __restrict__ w_im,
    const bf16x8* __restrict__ wsA, float2* __restrict__ wsP, int steps)
{
    const int lane = threadIdx.x & 63;
    const int wave = threadIdx.x >> 6;
    const int h    = lane >> 5;
    const int l32  = lane & 31;
    const int n    = blockIdx.x * 128 + wave * 32 + l32;
    const int s    = blockIdx.y;
    const int kbase = s * (steps * 8);   // complex-k base of this split

    f32x16 accR = {};
    f32x16 accI = {};

    const bf16x8* aptr = wsA + ((size_t)(kbase >> 2) + h) * 32 + l32;
    const float* pre = w_re + (size_t)(kbase + h * 4) * NN + n;
    const float* pim = w_im + (size_t)(kbase + h * 4) * NN + n;

#pragma unroll 4
    for (int t = 0; t < steps; ++t) {
        bf16x8 afrag = aptr[(size_t)(2 * t) * 32];
        const float* pr = pre + (size_t)t * 8 * NN;
        const float* pi = pim + (size_t)t * 8 * NN;
        float r0 = pr[0], r1 = pr[NN], r2 = pr[2 * NN], r3 = pr[3 * NN];
        float i0 = pi[0], i1 = pi[NN], i2 = pi[2 * NN], i3 = pi[3 * NN];

        bf16x8 bR, bI;
        bR[0] = (short)f2bf(r0);  bR[1] = (short)f2bf(-i0);
        bR[2] = (short)f2bf(r1);  bR[3] = (short)f2bf(-i1);
        bR[4] = (short)f2bf(r2);  bR[5] = (short)f2bf(-i2);
        bR[6] = (short)f2bf(r3);  bR[7] = (short)f2bf(-i3);
        bI[0] = (short)f2bf(i0);  bI[1] = (short)f2bf(r0);
        bI[2] = (short)f2bf(i1);  bI[3] = (short)f2bf(r1);
        bI[4] = (short)f2bf(i2);  bI[5] = (short)f2bf(r2);
        bI[6] = (short)f2bf(i3);  bI[7] = (short)f2bf(r3);

        accR = __builtin_amdgcn_mfma_f32_32x32x16_bf16(afrag, bR, accR, 0, 0, 0);
        accI = __builtin_amdgcn_mfma_f32_32x32x16_bf16(afrag, bI, accI, 0, 0, 0);
    }

    // C/D layout (32x32, verified m74/m101): col = lane&31 (=n),
    // row(batch) = (reg&3) + 8*(reg>>2) + 4*h
#pragma unroll
    for (int r = 0; r < 16; ++r) {
        int brow = (r & 3) + 8 * (r >> 2) + 4 * h;
        float2 v; v.x = accR[r]; v.y = accI[r];
        wsP[((size_t)s * NB + brow) * NN + n] = v;
    }
}

// ---------------------------------------------------------------------------
// Kernel 3: planar output (proven R5): out[b*4096+n]=re, out[HALF+..]=im
// ---------------------------------------------------------------------------
__global__ __launch_bounds__(256) void reduce_kernel(
    const float2* __restrict__ wsP, float* __restrict__ out, int S)
{
    int tid = blockIdx.x * 256 + threadIdx.x;   // 131072 complex
    float re = 0.f, im = 0.f;
    for (int s = 0; s < S; ++s) {
        float2 v = wsP[(size_t)s * (NB * NN) + tid];
        re += v.x; im += v.y;
    }
    out[tid]        = re;
    out[HALF + tid] = im;
}

extern "C" void kernel_launch(void* const* d_in, const int* in_sizes, int n_in,
                              void* d_out, int out_size, void* d_ws, size_t ws_size,
                              hipStream_t stream)
{
    const float* in_re  = (const float*)d_in[0];
    const float* in_im  = (const float*)d_in[1];
    const float* w_re   = (const float*)d_in[2];
    const float* w_im   = (const float*)d_in[3];
    const float* amp    = (const float*)d_in[4];
    const float* phase  = (const float*)d_in[5];

    const size_t A_BYTES = (size_t)1024 * 32 * 16;   // 512 KB bf16 A-fragments
    uint32_t* wsA = (uint32_t*)d_ws;
    float2*   wsP = (float2*)((char*)d_ws + A_BYTES);

    int S = 16;
    while (S > 1 && A_BYTES + (size_t)S * NB * NN * sizeof(float2) > ws_size) S >>= 1;
    int steps = (KC / S) / 8;

    prep_kernel<<<dim3((NB * KC) / 256), dim3(256), 0, stream>>>(
        in_re, in_im, amp, phase, wsA);

    gemm_kernel<<<dim3(NN / 128, S), dim3(256), 0, stream>>>(
        w_re, w_im, (const bf16x8*)wsA, wsP, steps);

    reduce_kernel<<<dim3((NB * NN) / 256), dim3(256), 0, stream>>>(
        wsP, (float*)d_out, S);
}